// Round 1
// baseline (1312.137 us; speedup 1.0000x reference)
//
#include <hip/hip_runtime.h>
#include <hip/hip_bf16.h>
#include <math.h>

#define B_   64
#define T_   32
#define S_   31      // scan steps = T-1
#define V_   10000
#define E_   300
#define H_   256
#define F_   4096
#define G4   1024    // 4*H
#define HE   556     // H+E
#define MPAD 2048    // S_*B_ = 1984 padded to 2048
#define NPAD 10112   // V padded to 79*128
#define START_ID 1

typedef __bf16 bf16x8 __attribute__((ext_vector_type(8)));
typedef float  f32x4  __attribute__((ext_vector_type(4)));

// ---------------- prep: fc2_w -> bf16 (padded rows zeroed), zero Hs pad rows
__global__ void k_prep(const float* __restrict__ fc2_w,
                       __hip_bfloat16* __restrict__ fc2bf,
                       __hip_bfloat16* __restrict__ Hs) {
    size_t i = (size_t)blockIdx.x * 256 + threadIdx.x;   // < NPAD*H_
    float v = (i < (size_t)V_ * H_) ? fc2_w[i] : 0.f;
    fc2bf[i] = __float2bfloat16(v);
    if (i < (size_t)(MPAD - S_ * B_) * H_) {             // zero A-pad rows
        Hs[(size_t)S_ * B_ * H_ + i] = __float2bfloat16(0.f);
    }
}

// ---------------- one-hot rows at t=0
__global__ void k_onehot(float* __restrict__ out) {
    int i = blockIdx.x * 256 + threadIdx.x;
    if (i < B_ * V_) {
        int b = i / V_, v = i - b * V_;
        out[(size_t)b * T_ * V_ + v] = (v == START_ID) ? 1.f : 0.f;
    }
}

// ---------------- Xp = X @ fc1_w.T + fc1_b   (64 x 256)
__global__ void k_xp(const float* __restrict__ X, const float* __restrict__ fc1_w,
                     const float* __restrict__ fc1_b, float* __restrict__ Xp) {
    __shared__ __align__(16) float xs[F_];
    int b = blockIdx.x;
    const float4* xrow = (const float4*)(X + (size_t)b * F_);
    for (int i = threadIdx.x; i < F_ / 4; i += 256) ((float4*)xs)[i] = xrow[i];
    __syncthreads();
    int k = threadIdx.x;
    const float4* w = (const float4*)(fc1_w + (size_t)k * F_);
    float acc = 0.f;
    #pragma unroll 8
    for (int f = 0; f < F_ / 4; ++f) {
        float4 wv = w[f];
        float4 xv = ((const float4*)xs)[f];
        acc += wv.x * xv.x + wv.y * xv.y + wv.z * xv.z + wv.w * xv.w;
    }
    Xp[b * H_ + k] = acc + fc1_b[k];
}

// ---------------- gconst = Xp @ w_ih[:, :H].T + b_ih + b_hh   (64 x 1024)
__global__ void k_gconst(const float* __restrict__ Xp, const float* __restrict__ w_ih,
                         const float* __restrict__ b_ih, const float* __restrict__ b_hh,
                         float* __restrict__ gconst) {
    __shared__ __align__(16) float xs[H_];
    int b = blockIdx.x;
    xs[threadIdx.x] = Xp[b * H_ + threadIdx.x];
    __syncthreads();
    #pragma unroll
    for (int q = 0; q < 4; ++q) {
        int j = threadIdx.x + q * 256;
        const float* w = w_ih + (size_t)j * HE;    // row stride 556*4=2224B, 16B-aligned
        float acc = 0.f;
        #pragma unroll 8
        for (int k = 0; k < H_ / 4; ++k) {
            float4 wv = *(const float4*)(w + k * 4);
            float4 xv = ((const float4*)xs)[k];
            acc += wv.x * xv.x + wv.y * xv.y + wv.z * xv.z + wv.w * xv.w;
        }
        gconst[b * G4 + j] = acc + b_ih[j] + b_hh[j];
    }
}

// ---------------- ge[t][b][:] = embeds[t][b] @ w_ih[:, H:].T   (31 x 64 x 1024)
// grid (4 j-tiles, 8 b-tiles, 31 t), block 256
__global__ void k_ge(const float* __restrict__ emb, const int* __restrict__ label,
                     const float* __restrict__ w_ih, float* __restrict__ ge) {
    __shared__ __align__(16) float es[8][E_];
    int jt = blockIdx.x, bt = blockIdx.y, t = blockIdx.z;
    for (int i = threadIdx.x; i < 8 * E_; i += 256) {
        int b8 = i / E_, e = i - b8 * E_;
        int b = bt * 8 + b8;
        int idx = (t == 0) ? START_ID : label[t * B_ + b];
        es[b8][e] = emb[(size_t)idx * E_ + e];
    }
    __syncthreads();
    int j = jt * 256 + threadIdx.x;
    const float* w = w_ih + (size_t)j * HE + H_;   // cols 256..555, 1024B offset: aligned
    float acc[8] = {0.f, 0.f, 0.f, 0.f, 0.f, 0.f, 0.f, 0.f};
    for (int kk = 0; kk < E_ / 4; ++kk) {
        float4 wv = *(const float4*)(w + kk * 4);
        #pragma unroll
        for (int b8 = 0; b8 < 8; ++b8) {
            float4 ev = *(const float4*)(&es[b8][kk * 4]);
            acc[b8] += wv.x * ev.x + wv.y * ev.y + wv.z * ev.z + wv.w * ev.w;
        }
    }
    #pragma unroll
    for (int b8 = 0; b8 < 8; ++b8)
        ge[((size_t)t * B_ + bt * 8 + b8) * G4 + j] = acc[b8];
}

// ---------------- LSTM recurrence: one block per batch row, all 31 steps
__global__ __launch_bounds__(1024) void k_lstm(const float* __restrict__ gconst,
                                               const float* __restrict__ ge,
                                               const float* __restrict__ w_hh,
                                               __hip_bfloat16* __restrict__ Hs) {
    int b = blockIdx.x;
    int j = threadIdx.x;                  // 0..1023 gate row
    __shared__ __align__(16) float hs[H_];
    __shared__ float gs[G4];
    float c = 0.f;
    if (j < H_) hs[j] = 0.f;
    float gc = gconst[b * G4 + j];
    const float4* w = (const float4*)(w_hh + (size_t)j * H_);
    __syncthreads();
    for (int t = 0; t < S_; ++t) {
        float acc = gc + ge[((size_t)t * B_ + b) * G4 + j];
        #pragma unroll 8
        for (int k = 0; k < H_ / 4; ++k) {
            float4 wv = w[k];
            float4 hv = ((const float4*)hs)[k];
            acc += wv.x * hv.x + wv.y * hv.y + wv.z * hv.z + wv.w * hv.w;
        }
        gs[j] = acc;
        __syncthreads();
        if (j < H_) {
            float ig = 1.f / (1.f + __expf(-gs[j]));
            float fg = 1.f / (1.f + __expf(-gs[j + 256]));
            float gg = tanhf(gs[j + 512]);
            float og = 1.f / (1.f + __expf(-gs[j + 768]));
            c = fg * c + ig * gg;
            float h = og * tanhf(c);
            hs[j] = h;
            Hs[((size_t)t * B_ + b) * H_ + j] = __float2bfloat16(h);
        }
        __syncthreads();
    }
}

// ---------------- logits = Hs @ fc2_w.T + fc2_b -> out[b][t+1][v]  (bf16 MFMA)
// grid (79 n-tiles, 16 m-tiles), block 256 = 4 waves, 128x128 block tile, 64x64/wave
__global__ __launch_bounds__(256) void k_gemm(const unsigned short* __restrict__ A,   // MPAD x 256 bf16
                                              const unsigned short* __restrict__ Bw,  // NPAD x 256 bf16
                                              const float* __restrict__ bias,
                                              float* __restrict__ out) {
    int nt = blockIdx.x, mt = blockIdx.y;
    int w = threadIdx.x >> 6, lane = threadIdx.x & 63;
    int l16 = lane & 15, quad = lane >> 4;
    int m0 = mt * 128 + (w >> 1) * 64;
    int n0 = nt * 128 + (w & 1) * 64;
    f32x4 acc[4][4] = {};
    const unsigned short* Ap = A + (size_t)(m0 + l16) * H_ + quad * 8;
    const unsigned short* Bp = Bw + (size_t)(n0 + l16) * H_ + quad * 8;
    #pragma unroll
    for (int k = 0; k < H_; k += 32) {
        bf16x8 a[4], bb[4];
        #pragma unroll
        for (int i = 0; i < 4; ++i) {
            a[i]  = *(const bf16x8*)(Ap + (size_t)i * 16 * H_ + k);
            bb[i] = *(const bf16x8*)(Bp + (size_t)i * 16 * H_ + k);
        }
        #pragma unroll
        for (int i = 0; i < 4; ++i)
            #pragma unroll
            for (int jn = 0; jn < 4; ++jn)
                acc[i][jn] = __builtin_amdgcn_mfma_f32_16x16x32_bf16(a[i], bb[jn], acc[i][jn], 0, 0, 0);
    }
    // D[row=m][col=n]: m = m0+i*16+quad*4+r, n = n0+jn*16+l16   [m89/m91 layout]
    #pragma unroll
    for (int i = 0; i < 4; ++i) {
        #pragma unroll
        for (int jn = 0; jn < 4; ++jn) {
            #pragma unroll
            for (int r = 0; r < 4; ++r) {
                int m = m0 + i * 16 + quad * 4 + r;
                int n = n0 + jn * 16 + l16;
                if (m < S_ * B_ && n < V_) {
                    int t = m >> 6, b = m & 63;
                    out[((size_t)b * T_ + t + 1) * V_ + n] = acc[i][jn][r] + bias[n];
                }
            }
        }
    }
}

// ---------------- in-place log_softmax over V per (t,b) row
__global__ void k_lsm(float* __restrict__ out) {
    __shared__ float red[256];
    int m = blockIdx.x;                   // 0..1983, m = t*64+b
    int t = m >> 6, b = m & 63;
    float* row = out + ((size_t)b * T_ + t + 1) * V_;
    int tid = threadIdx.x;
    float mx = -1e30f;
    for (int v = tid; v < V_; v += 256) mx = fmaxf(mx, row[v]);
    red[tid] = mx; __syncthreads();
    for (int s = 128; s > 0; s >>= 1) {
        if (tid < s) red[tid] = fmaxf(red[tid], red[tid + s]);
        __syncthreads();
    }
    float mxv = red[0];
    __syncthreads();
    float sum = 0.f;
    for (int v = tid; v < V_; v += 256) sum += __expf(row[v] - mxv);
    red[tid] = sum; __syncthreads();
    for (int s = 128; s > 0; s >>= 1) {
        if (tid < s) red[tid] += red[tid + s];
        __syncthreads();
    }
    float lse = mxv + logf(red[0]);
    for (int v = tid; v < V_; v += 256) row[v] -= lse;
}

extern "C" void kernel_launch(void* const* d_in, const int* in_sizes, int n_in,
                              void* d_out, int out_size, void* d_ws, size_t ws_size,
                              hipStream_t stream) {
    const float* X      = (const float*)d_in[0];
    const float* emb    = (const float*)d_in[1];
    const float* fc1_w  = (const float*)d_in[2];
    const float* fc1_b  = (const float*)d_in[3];
    const float* w_ih   = (const float*)d_in[4];
    const float* w_hh   = (const float*)d_in[5];
    const float* b_ih   = (const float*)d_in[6];
    const float* b_hh   = (const float*)d_in[7];
    const float* fc2_w  = (const float*)d_in[8];
    const float* fc2_b  = (const float*)d_in[9];
    const int*   label  = (const int*)d_in[10];
    float* out = (float*)d_out;

    char* ws = (char*)d_ws;
    float* Xp      = (float*)(ws);                       // 64*256*4      = 65536
    float* gconst  = (float*)(ws + 65536);               // 64*1024*4     = 262144
    float* ge      = (float*)(ws + 327680);              // 31*64*1024*4  = 8126464
    __hip_bfloat16* Hs    = (__hip_bfloat16*)(ws + 8454144);   // 2048*256*2  = 1048576
    __hip_bfloat16* fc2bf = (__hip_bfloat16*)(ws + 9502720);   // 10112*256*2 = 5177344
    // total = 14680064 bytes

    k_prep  <<<NPAD, 256, 0, stream>>>(fc2_w, fc2bf, Hs);
    k_onehot<<<(B_ * V_ + 255) / 256, 256, 0, stream>>>(out);
    k_xp    <<<B_, 256, 0, stream>>>(X, fc1_w, fc1_b, Xp);
    k_gconst<<<B_, 256, 0, stream>>>(Xp, w_ih, b_ih, b_hh, gconst);
    k_ge    <<<dim3(4, 8, S_), 256, 0, stream>>>(emb, label, w_ih, ge);
    k_lstm  <<<B_, 1024, 0, stream>>>(gconst, ge, w_hh, Hs);
    k_gemm  <<<dim3(NPAD / 128, MPAD / 128), 256, 0, stream>>>((const unsigned short*)Hs,
                                                              (const unsigned short*)fc2bf, fc2_b, out);
    k_lsm   <<<S_ * B_, 256, 0, stream>>>(out);
}

// Round 2
// 673.492 us; speedup vs baseline: 1.9483x; 1.9483x over previous
//
#include <hip/hip_runtime.h>
#include <hip/hip_bf16.h>
#include <math.h>

#define B_   64
#define T_   32
#define S_   31      // scan steps = T-1
#define V_   10000
#define E_   300
#define H_   256
#define F_   4096
#define G4   1024    // 4*H
#define HE   556     // H+E
#define MPAD 2048    // S_*B_ = 1984 padded to 2048
#define NPAD 10112   // V padded to 79*128
#define START_ID 1

typedef __bf16 bf16x8 __attribute__((ext_vector_type(8)));
typedef float  f32x4  __attribute__((ext_vector_type(4)));

__device__ __forceinline__ float bf16bits_to_f(unsigned int u) {
    union { unsigned int i; float f; } c; c.i = u; return c.f;
}
__device__ __forceinline__ unsigned short f_to_bf16bits(float f) {
    union { float f; unsigned int i; } c; c.f = f;
    unsigned int r = c.i + 0x7fffu + ((c.i >> 16) & 1);   // RNE
    return (unsigned short)(r >> 16);
}

// ---------------- prep: fc2_w -> bf16 (padded rows zeroed), zero Hs pad rows,
// and build wp: k-major packed-bf16 transpose of w_hh.
// wp viewed as uint2[64][1024]: wp[k4][j] = 4 bf16 of w_hh[j][4k4..4k4+3]
__global__ void k_prep(const float* __restrict__ fc2_w, const float* __restrict__ w_hh,
                       __hip_bfloat16* __restrict__ fc2bf,
                       __hip_bfloat16* __restrict__ Hs,
                       uint2* __restrict__ wp) {
    size_t i = (size_t)blockIdx.x * 256 + threadIdx.x;   // < NPAD*H_
    float v = (i < (size_t)V_ * H_) ? fc2_w[i] : 0.f;
    fc2bf[i] = __float2bfloat16(v);
    if (i < (size_t)(MPAD - S_ * B_) * H_) {             // zero A-pad rows
        Hs[(size_t)S_ * B_ * H_ + i] = __float2bfloat16(0.f);
    }
    if (i < 64 * 1024) {                                 // transpose+pack w_hh
        int k4 = (int)(i >> 10), j = (int)(i & 1023);
        float4 w = *(const float4*)(w_hh + (size_t)j * H_ + 4 * k4);
        uint2 p;
        p.x = (unsigned int)f_to_bf16bits(w.x) | ((unsigned int)f_to_bf16bits(w.y) << 16);
        p.y = (unsigned int)f_to_bf16bits(w.z) | ((unsigned int)f_to_bf16bits(w.w) << 16);
        wp[i] = p;
    }
}

// ---------------- one-hot rows at t=0
__global__ void k_onehot(float* __restrict__ out) {
    int i = blockIdx.x * 256 + threadIdx.x;
    if (i < B_ * V_) {
        int b = i / V_, v = i - b * V_;
        out[(size_t)b * T_ * V_ + v] = (v == START_ID) ? 1.f : 0.f;
    }
}

// ---------------- Xp = X @ fc1_w.T + fc1_b   (64 x 256)
__global__ void k_xp(const float* __restrict__ X, const float* __restrict__ fc1_w,
                     const float* __restrict__ fc1_b, float* __restrict__ Xp) {
    __shared__ __align__(16) float xs[F_];
    int b = blockIdx.x;
    const float4* xrow = (const float4*)(X + (size_t)b * F_);
    for (int i = threadIdx.x; i < F_ / 4; i += 256) ((float4*)xs)[i] = xrow[i];
    __syncthreads();
    int k = threadIdx.x;
    const float4* w = (const float4*)(fc1_w + (size_t)k * F_);
    float acc = 0.f;
    #pragma unroll 8
    for (int f = 0; f < F_ / 4; ++f) {
        float4 wv = w[f];
        float4 xv = ((const float4*)xs)[f];
        acc += wv.x * xv.x + wv.y * xv.y + wv.z * xv.z + wv.w * xv.w;
    }
    Xp[b * H_ + k] = acc + fc1_b[k];
}

// ---------------- gconst = Xp @ w_ih[:, :H].T + b_ih + b_hh   (64 x 1024)
__global__ void k_gconst(const float* __restrict__ Xp, const float* __restrict__ w_ih,
                         const float* __restrict__ b_ih, const float* __restrict__ b_hh,
                         float* __restrict__ gconst) {
    __shared__ __align__(16) float xs[H_];
    int b = blockIdx.x;
    xs[threadIdx.x] = Xp[b * H_ + threadIdx.x];
    __syncthreads();
    #pragma unroll
    for (int q = 0; q < 4; ++q) {
        int j = threadIdx.x + q * 256;
        const float* w = w_ih + (size_t)j * HE;
        float acc = 0.f;
        #pragma unroll 8
        for (int k = 0; k < H_ / 4; ++k) {
            float4 wv = *(const float4*)(w + k * 4);
            float4 xv = ((const float4*)xs)[k];
            acc += wv.x * xv.x + wv.y * xv.y + wv.z * xv.z + wv.w * xv.w;
        }
        gconst[b * G4 + j] = acc + b_ih[j] + b_hh[j];
    }
}

// ---------------- ge[t][b][:] = embeds[t][b] @ w_ih[:, H:].T   (31 x 64 x 1024), bf16 out
__global__ void k_ge(const float* __restrict__ emb, const int* __restrict__ label,
                     const float* __restrict__ w_ih, __hip_bfloat16* __restrict__ ge) {
    __shared__ __align__(16) float es[8][E_];
    int jt = blockIdx.x, bt = blockIdx.y, t = blockIdx.z;
    for (int i = threadIdx.x; i < 8 * E_; i += 256) {
        int b8 = i / E_, e = i - b8 * E_;
        int b = bt * 8 + b8;
        int idx = (t == 0) ? START_ID : label[t * B_ + b];
        es[b8][e] = emb[(size_t)idx * E_ + e];
    }
    __syncthreads();
    int j = jt * 256 + threadIdx.x;
    const float* w = w_ih + (size_t)j * HE + H_;
    float acc[8] = {0.f, 0.f, 0.f, 0.f, 0.f, 0.f, 0.f, 0.f};
    for (int kk = 0; kk < E_ / 4; ++kk) {
        float4 wv = *(const float4*)(w + kk * 4);
        #pragma unroll
        for (int b8 = 0; b8 < 8; ++b8) {
            float4 ev = *(const float4*)(&es[b8][kk * 4]);
            acc[b8] += wv.x * ev.x + wv.y * ev.y + wv.z * ev.z + wv.w * ev.w;
        }
    }
    #pragma unroll
    for (int b8 = 0; b8 < 8; ++b8)
        ge[((size_t)t * B_ + bt * 8 + b8) * G4 + j] = __float2bfloat16(acc[b8]);
}

// ---------------- LSTM recurrence: one block per batch row, all 31 steps
// w read from wp (k-major packed bf16) -> fully coalesced 8B/lane loads
__global__ __launch_bounds__(1024) void k_lstm(const float* __restrict__ gconst,
                                               const unsigned short* __restrict__ gebf,
                                               const uint2* __restrict__ wp,
                                               __hip_bfloat16* __restrict__ Hs) {
    int b = blockIdx.x;
    int j = threadIdx.x;                  // 0..1023 gate row
    __shared__ __align__(16) float hsf[H_];
    __shared__ float gs[G4];
    float c = 0.f;
    if (j < H_) hsf[j] = 0.f;
    float gc = gconst[b * G4 + j];
    __syncthreads();
    for (int t = 0; t < S_; ++t) {
        float acc = gc + bf16bits_to_f((unsigned int)gebf[((size_t)t * B_ + b) * G4 + j] << 16);
        #pragma unroll 16
        for (int k4 = 0; k4 < H_ / 4; ++k4) {
            uint2 wv = wp[k4 * G4 + j];                      // coalesced, lane-contiguous
            float4 hv = *(const float4*)(hsf + k4 * 4);      // LDS broadcast
            float w0 = bf16bits_to_f(wv.x << 16);
            float w1 = bf16bits_to_f(wv.x & 0xffff0000u);
            float w2 = bf16bits_to_f(wv.y << 16);
            float w3 = bf16bits_to_f(wv.y & 0xffff0000u);
            acc += hv.x * w0 + hv.y * w1 + hv.z * w2 + hv.w * w3;
        }
        gs[j] = acc;
        __syncthreads();
        if (j < H_) {
            float ig = 1.f / (1.f + __expf(-gs[j]));
            float fg = 1.f / (1.f + __expf(-gs[j + 256]));
            float gg = tanhf(gs[j + 512]);
            float og = 1.f / (1.f + __expf(-gs[j + 768]));
            c = fg * c + ig * gg;
            float h = og * tanhf(c);
            hsf[j] = h;
            Hs[((size_t)t * B_ + b) * H_ + j] = __float2bfloat16(h);
        }
        __syncthreads();
    }
}

// ---------------- logits = Hs @ fc2_w.T + fc2_b -> out[b][t+1][v]  (bf16 MFMA)
__global__ __launch_bounds__(256) void k_gemm(const unsigned short* __restrict__ A,   // MPAD x 256 bf16
                                              const unsigned short* __restrict__ Bw,  // NPAD x 256 bf16
                                              const float* __restrict__ bias,
                                              float* __restrict__ out) {
    int nt = blockIdx.x, mt = blockIdx.y;
    int w = threadIdx.x >> 6, lane = threadIdx.x & 63;
    int l16 = lane & 15, quad = lane >> 4;
    int m0 = mt * 128 + (w >> 1) * 64;
    int n0 = nt * 128 + (w & 1) * 64;
    f32x4 acc[4][4] = {};
    const unsigned short* Ap = A + (size_t)(m0 + l16) * H_ + quad * 8;
    const unsigned short* Bp = Bw + (size_t)(n0 + l16) * H_ + quad * 8;
    #pragma unroll
    for (int k = 0; k < H_; k += 32) {
        bf16x8 a[4], bb[4];
        #pragma unroll
        for (int i = 0; i < 4; ++i) {
            a[i]  = *(const bf16x8*)(Ap + (size_t)i * 16 * H_ + k);
            bb[i] = *(const bf16x8*)(Bp + (size_t)i * 16 * H_ + k);
        }
        #pragma unroll
        for (int i = 0; i < 4; ++i)
            #pragma unroll
            for (int jn = 0; jn < 4; ++jn)
                acc[i][jn] = __builtin_amdgcn_mfma_f32_16x16x32_bf16(a[i], bb[jn], acc[i][jn], 0, 0, 0);
    }
    #pragma unroll
    for (int i = 0; i < 4; ++i) {
        #pragma unroll
        for (int jn = 0; jn < 4; ++jn) {
            #pragma unroll
            for (int r = 0; r < 4; ++r) {
                int m = m0 + i * 16 + quad * 4 + r;
                int n = n0 + jn * 16 + l16;
                if (m < S_ * B_ && n < V_) {
                    int t = m >> 6, b = m & 63;
                    out[((size_t)b * T_ + t + 1) * V_ + n] = acc[i][jn][r] + bias[n];
                }
            }
        }
    }
}

// ---------------- in-place log_softmax over V per (t,b) row — online 2-pass, float4
__global__ void k_lsm(float* __restrict__ out) {
    __shared__ float rmx[256], rsum[256];
    int m = blockIdx.x;                   // 0..1983, m = t*64+b
    int t = m >> 6, b = m & 63;
    float* row = out + ((size_t)b * T_ + t + 1) * V_;
    int tid = threadIdx.x;
    float mx = -1e30f, sum = 0.f;
    for (int v4 = tid; v4 < V_ / 4; v4 += 256) {
        float4 x = ((const float4*)row)[v4];
        float m4 = fmaxf(fmaxf(x.x, x.y), fmaxf(x.z, x.w));
        if (m4 > mx) { sum *= __expf(mx - m4); mx = m4; }
        sum += __expf(x.x - mx) + __expf(x.y - mx) + __expf(x.z - mx) + __expf(x.w - mx);
    }
    rmx[tid] = mx; rsum[tid] = sum;
    __syncthreads();
    for (int s = 128; s > 0; s >>= 1) {
        if (tid < s) {
            float ma = rmx[tid], mb = rmx[tid + s];
            float sa = rsum[tid], sb = rsum[tid + s];
            float mm = fmaxf(ma, mb);
            rmx[tid] = mm;
            rsum[tid] = sa * __expf(ma - mm) + sb * __expf(mb - mm);
        }
        __syncthreads();
    }
    float lse = rmx[0] + logf(rsum[0]);
    for (int v4 = tid; v4 < V_ / 4; v4 += 256) {
        float4 x = ((const float4*)row)[v4];
        x.x -= lse; x.y -= lse; x.z -= lse; x.w -= lse;
        ((float4*)row)[v4] = x;
    }
}

extern "C" void kernel_launch(void* const* d_in, const int* in_sizes, int n_in,
                              void* d_out, int out_size, void* d_ws, size_t ws_size,
                              hipStream_t stream) {
    const float* X      = (const float*)d_in[0];
    const float* emb    = (const float*)d_in[1];
    const float* fc1_w  = (const float*)d_in[2];
    const float* fc1_b  = (const float*)d_in[3];
    const float* w_ih   = (const float*)d_in[4];
    const float* w_hh   = (const float*)d_in[5];
    const float* b_ih   = (const float*)d_in[6];
    const float* b_hh   = (const float*)d_in[7];
    const float* fc2_w  = (const float*)d_in[8];
    const float* fc2_b  = (const float*)d_in[9];
    const int*   label  = (const int*)d_in[10];
    float* out = (float*)d_out;

    char* ws = (char*)d_ws;
    float* Xp      = (float*)(ws);                             // 65536
    float* gconst  = (float*)(ws + 65536);                     // 262144
    __hip_bfloat16* gebf  = (__hip_bfloat16*)(ws + 327680);    // 31*64*1024*2 = 4063232
    __hip_bfloat16* Hs    = (__hip_bfloat16*)(ws + 4390912);   // 2048*256*2   = 1048576
    __hip_bfloat16* fc2bf = (__hip_bfloat16*)(ws + 5439488);   // 10112*256*2  = 5177344
    uint2*          wp    = (uint2*)(ws + 10616832);           // 64*1024*8    = 524288
    // total = 11141120 bytes (< proven 14.68 MB budget)

    k_prep  <<<NPAD, 256, 0, stream>>>(fc2_w, w_hh, fc2bf, Hs, wp);
    k_onehot<<<(B_ * V_ + 255) / 256, 256, 0, stream>>>(out);
    k_xp    <<<B_, 256, 0, stream>>>(X, fc1_w, fc1_b, Xp);
    k_gconst<<<B_, 256, 0, stream>>>(Xp, w_ih, b_ih, b_hh, gconst);
    k_ge    <<<dim3(4, 8, S_), 256, 0, stream>>>(emb, label, w_ih, gebf);
    k_lstm  <<<B_, 1024, 0, stream>>>(gconst, (const unsigned short*)gebf, wp, Hs);
    k_gemm  <<<dim3(NPAD / 128, MPAD / 128), 256, 0, stream>>>((const unsigned short*)Hs,
                                                              (const unsigned short*)fc2bf, fc2_b, out);
    k_lsm   <<<S_ * B_, 256, 0, stream>>>(out);
}

// Round 3
// 611.606 us; speedup vs baseline: 2.1454x; 1.1012x over previous
//
#include <hip/hip_runtime.h>
#include <hip/hip_bf16.h>
#include <math.h>

#define B_   64
#define T_   32
#define S_   31      // scan steps = T-1
#define V_   10000
#define E_   300
#define H_   256
#define F_   4096
#define G4   1024    // 4*H
#define HE   556     // H+E
#define MPAD 2048    // S_*B_ = 1984 padded to 2048
#define NPAD 10112   // V padded to 79*128
#define START_ID 1
#define LBLK 64      // k_lstm blocks (must all be co-resident; 64 <= 256 CUs)

typedef __bf16 bf16x8 __attribute__((ext_vector_type(8)));
typedef float  f32x4  __attribute__((ext_vector_type(4)));

__device__ __forceinline__ float bf16bits_to_f(unsigned int u) {
    union { unsigned int i; float f; } c; c.i = u; return c.f;
}
__device__ __forceinline__ unsigned short f_to_bf16bits(float f) {
    union { float f; unsigned int i; } c; c.f = f;
    unsigned int r = c.i + 0x7fffu + ((c.i >> 16) & 1);   // RNE
    return (unsigned short)(r >> 16);
}
__device__ __forceinline__ float sigm(float x) { return 1.f / (1.f + __expf(-x)); }
__device__ __forceinline__ float tanh_fast(float x) { return 1.f - 2.f / (__expf(2.f * x) + 1.f); }

// ---------------- prep: fc2_w -> bf16 (pad rows zeroed), zero Hs pad rows,
// zero h0 double-buffer slot 0, zero grid-barrier counter
__global__ void k_prep(const float* __restrict__ fc2_w,
                       __hip_bfloat16* __restrict__ fc2bf,
                       __hip_bfloat16* __restrict__ Hs,
                       unsigned short* __restrict__ h0,
                       unsigned int* __restrict__ bar) {
    size_t i = (size_t)blockIdx.x * 256 + threadIdx.x;   // < NPAD*H_
    float v = (i < (size_t)V_ * H_) ? fc2_w[i] : 0.f;
    fc2bf[i] = __float2bfloat16(v);
    if (i < (size_t)(MPAD - S_ * B_) * H_)
        Hs[(size_t)S_ * B_ * H_ + i] = __float2bfloat16(0.f);
    if (i < B_ * H_) h0[i] = 0;                          // h(-1) = 0 (bf16 zero bits)
    if (i == 0) *bar = 0u;
}

// ---------------- one-hot rows at t=0
__global__ void k_onehot(float* __restrict__ out) {
    int i = blockIdx.x * 256 + threadIdx.x;
    if (i < B_ * V_) {
        int b = i / V_, v = i - b * V_;
        out[(size_t)b * T_ * V_ + v] = (v == START_ID) ? 1.f : 0.f;
    }
}

// ---------------- Xp = X @ fc1_w.T + fc1_b   (64 x 256)
__global__ void k_xp(const float* __restrict__ X, const float* __restrict__ fc1_w,
                     const float* __restrict__ fc1_b, float* __restrict__ Xp) {
    __shared__ __align__(16) float xs[F_];
    int b = blockIdx.x;
    const float4* xrow = (const float4*)(X + (size_t)b * F_);
    for (int i = threadIdx.x; i < F_ / 4; i += 256) ((float4*)xs)[i] = xrow[i];
    __syncthreads();
    int k = threadIdx.x;
    const float4* w = (const float4*)(fc1_w + (size_t)k * F_);
    float acc = 0.f;
    #pragma unroll 8
    for (int f = 0; f < F_ / 4; ++f) {
        float4 wv = w[f];
        float4 xv = ((const float4*)xs)[f];
        acc += wv.x * xv.x + wv.y * xv.y + wv.z * xv.z + wv.w * xv.w;
    }
    Xp[b * H_ + k] = acc + fc1_b[k];
}

// ---------------- gconst = Xp @ w_ih[:, :H].T + b_ih + b_hh   (64 x 1024)
__global__ void k_gconst(const float* __restrict__ Xp, const float* __restrict__ w_ih,
                         const float* __restrict__ b_ih, const float* __restrict__ b_hh,
                         float* __restrict__ gconst) {
    __shared__ __align__(16) float xs[H_];
    int b = blockIdx.x;
    xs[threadIdx.x] = Xp[b * H_ + threadIdx.x];
    __syncthreads();
    #pragma unroll
    for (int q = 0; q < 4; ++q) {
        int j = threadIdx.x + q * 256;
        const float* w = w_ih + (size_t)j * HE;
        float acc = 0.f;
        #pragma unroll 8
        for (int k = 0; k < H_ / 4; ++k) {
            float4 wv = *(const float4*)(w + k * 4);
            float4 xv = ((const float4*)xs)[k];
            acc += wv.x * xv.x + wv.y * xv.y + wv.z * xv.z + wv.w * xv.w;
        }
        gconst[b * G4 + j] = acc + b_ih[j] + b_hh[j];
    }
}

// ---------------- gfullT[t][g][n][b] = gconst[b][j] + embeds[t][b] @ w_ih[j, H:]  (bf16)
// j = gate*256 + g*4 + u ; n = gate*4 + u  (MFMA-C-tile friendly layout)
__global__ void k_ge(const float* __restrict__ emb, const int* __restrict__ label,
                     const float* __restrict__ w_ih, const float* __restrict__ gconst,
                     unsigned short* __restrict__ gfullT) {
    __shared__ __align__(16) float es[8][E_];
    int jt = blockIdx.x, bt = blockIdx.y, t = blockIdx.z;
    for (int i = threadIdx.x; i < 8 * E_; i += 256) {
        int b8 = i / E_, e = i - b8 * E_;
        int b = bt * 8 + b8;
        int idx = (t == 0) ? START_ID : label[t * B_ + b];
        es[b8][e] = emb[(size_t)idx * E_ + e];
    }
    __syncthreads();
    int j = jt * 256 + threadIdx.x;
    const float* w = w_ih + (size_t)j * HE + H_;
    float acc[8] = {0.f, 0.f, 0.f, 0.f, 0.f, 0.f, 0.f, 0.f};
    for (int kk = 0; kk < E_ / 4; ++kk) {
        float4 wv = *(const float4*)(w + kk * 4);
        #pragma unroll
        for (int b8 = 0; b8 < 8; ++b8) {
            float4 ev = *(const float4*)(&es[b8][kk * 4]);
            acc[b8] += wv.x * ev.x + wv.y * ev.y + wv.z * ev.z + wv.w * ev.w;
        }
    }
    int gate = j >> 8, hidx = j & 255;
    int g = hidx >> 2, u = hidx & 3;
    int n = gate * 4 + u;
    size_t base = ((size_t)(t * 64 + g) * 16 + n) * 64 + bt * 8;
    unsigned short pk[8];
    #pragma unroll
    for (int b8 = 0; b8 < 8; ++b8)
        pk[b8] = f_to_bf16bits(acc[b8] + gconst[(bt * 8 + b8) * G4 + j]);
    uint4 st;
    st.x = (unsigned)pk[0] | ((unsigned)pk[1] << 16);
    st.y = (unsigned)pk[2] | ((unsigned)pk[3] << 16);
    st.z = (unsigned)pk[4] | ((unsigned)pk[5] << 16);
    st.w = (unsigned)pk[6] | ((unsigned)pk[7] << 16);
    *(uint4*)(gfullT + base) = st;
}

// ---------------- LSTM recurrence: persistent cooperative kernel, MFMA per step
// 64 blocks x 256 thr. Block g owns hidden units [g*4, g*4+4) = 16 gate rows;
// w_hh slice lives in registers as MFMA B-fragments for all 31 steps.
__global__ __launch_bounds__(256) void k_lstm(const unsigned short* __restrict__ gfullT,
                                              const float* __restrict__ w_hh,
                                              unsigned short* __restrict__ hbuf0,
                                              unsigned short* __restrict__ hbuf1,
                                              __hip_bfloat16* __restrict__ Hs,
                                              unsigned int* __restrict__ bar) {
    int g = blockIdx.x;
    int tid = threadIdx.x;
    int w = tid >> 6, lane = tid & 63;
    int l16 = lane & 15, quad = lane >> 4;
    __shared__ float gs[16][81];   // [n][batch], pad 81 (17 mod 32) -> <=2-way conflicts

    // one-time: B fragments from w_hh (f32 -> bf16), n = l16 = gate*4+u
    int gate = l16 >> 2, u = l16 & 3;
    int jg = gate * 256 + g * 4 + u;
    const float* wrow = w_hh + (size_t)jg * H_ + quad * 8;
    bf16x8 bfrag[8];
    #pragma unroll
    for (int kk = 0; kk < 8; ++kk) {
        float4 a0 = *(const float4*)(wrow + kk * 32);
        float4 a1 = *(const float4*)(wrow + kk * 32 + 4);
        union { unsigned short s[8]; bf16x8 v; } pk;
        pk.s[0] = f_to_bf16bits(a0.x); pk.s[1] = f_to_bf16bits(a0.y);
        pk.s[2] = f_to_bf16bits(a0.z); pk.s[3] = f_to_bf16bits(a0.w);
        pk.s[4] = f_to_bf16bits(a1.x); pk.s[5] = f_to_bf16bits(a1.y);
        pk.s[6] = f_to_bf16bits(a1.z); pk.s[7] = f_to_bf16bits(a1.w);
        bfrag[kk] = pk.v;
    }

    int b = tid >> 2, uu = tid & 3;   // gate-math ownership: (batch b, hidden g*4+uu)
    float c = 0.f;

    for (int t = 0; t < S_; ++t) {
        const unsigned short* hr = (t & 1) ? hbuf1 : hbuf0;
        unsigned short* hw = (t & 1) ? hbuf0 : hbuf1;

        // C-init from gfullT (bf16 -> f32), exactly the MFMA C layout
        const unsigned short* gp = gfullT + ((size_t)(t * 64 + g) * 16 + l16) * 64 + w * 16 + quad * 4;
        uint2 cp = *(const uint2*)gp;
        f32x4 acc;
        acc[0] = bf16bits_to_f(cp.x << 16);
        acc[1] = bf16bits_to_f(cp.x & 0xffff0000u);
        acc[2] = bf16bits_to_f(cp.y << 16);
        acc[3] = bf16bits_to_f(cp.y & 0xffff0000u);

        const unsigned short* ha = hr + (size_t)(w * 16 + l16) * H_ + quad * 8;
        #pragma unroll
        for (int kk = 0; kk < 8; ++kk) {
            bf16x8 af = *(const bf16x8*)(ha + kk * 32);
            acc = __builtin_amdgcn_mfma_f32_16x16x32_bf16(af, bfrag[kk], acc, 0, 0, 0);
        }
        #pragma unroll
        for (int r = 0; r < 4; ++r)
            gs[l16][w * 16 + quad * 4 + r] = acc[r];
        __syncthreads();

        float ig = sigm(gs[uu][b]);
        float fg = sigm(gs[4 + uu][b]);
        float gg = tanh_fast(gs[8 + uu][b]);
        float og = sigm(gs[12 + uu][b]);
        c = fg * c + ig * gg;
        float h = og * tanh_fast(c);
        unsigned short hb = f_to_bf16bits(h);
        hw[b * H_ + g * 4 + uu] = hb;
        *(unsigned short*)&Hs[((size_t)t * B_ + b) * H_ + g * 4 + uu] = hb;

        // grid barrier (monotone counter; release h-writes, acquire before next reads)
        __syncthreads();
        if (tid == 0) {
            __hip_atomic_fetch_add(bar, 1u, __ATOMIC_ACQ_REL, __HIP_MEMORY_SCOPE_AGENT);
            unsigned target = (unsigned)LBLK * (t + 1);
            while (__hip_atomic_load(bar, __ATOMIC_ACQUIRE, __HIP_MEMORY_SCOPE_AGENT) < target)
                __builtin_amdgcn_s_sleep(2);
        }
        __syncthreads();
    }
}

// ---------------- logits = Hs @ fc2_w.T + fc2_b -> out[b][t+1][v]  (bf16 MFMA)
__global__ __launch_bounds__(256) void k_gemm(const unsigned short* __restrict__ A,   // MPAD x 256 bf16
                                              const unsigned short* __restrict__ Bw,  // NPAD x 256 bf16
                                              const float* __restrict__ bias,
                                              float* __restrict__ out) {
    int nt = blockIdx.x, mt = blockIdx.y;
    int w = threadIdx.x >> 6, lane = threadIdx.x & 63;
    int l16 = lane & 15, quad = lane >> 4;
    int m0 = mt * 128 + (w >> 1) * 64;
    int n0 = nt * 128 + (w & 1) * 64;
    f32x4 acc[4][4] = {};
    const unsigned short* Ap = A + (size_t)(m0 + l16) * H_ + quad * 8;
    const unsigned short* Bp = Bw + (size_t)(n0 + l16) * H_ + quad * 8;
    #pragma unroll
    for (int k = 0; k < H_; k += 32) {
        bf16x8 a[4], bb[4];
        #pragma unroll
        for (int i = 0; i < 4; ++i) {
            a[i]  = *(const bf16x8*)(Ap + (size_t)i * 16 * H_ + k);
            bb[i] = *(const bf16x8*)(Bp + (size_t)i * 16 * H_ + k);
        }
        #pragma unroll
        for (int i = 0; i < 4; ++i)
            #pragma unroll
            for (int jn = 0; jn < 4; ++jn)
                acc[i][jn] = __builtin_amdgcn_mfma_f32_16x16x32_bf16(a[i], bb[jn], acc[i][jn], 0, 0, 0);
    }
    #pragma unroll
    for (int i = 0; i < 4; ++i) {
        #pragma unroll
        for (int jn = 0; jn < 4; ++jn) {
            #pragma unroll
            for (int r = 0; r < 4; ++r) {
                int m = m0 + i * 16 + quad * 4 + r;
                int n = n0 + jn * 16 + l16;
                if (m < S_ * B_ && n < V_) {
                    int t = m >> 6, b = m & 63;
                    out[((size_t)b * T_ + t + 1) * V_ + n] = acc[i][jn][r] + bias[n];
                }
            }
        }
    }
}

// ---------------- in-place log_softmax over V per (t,b) row — online 2-pass, float4
__global__ void k_lsm(float* __restrict__ out) {
    __shared__ float rmx[256], rsum[256];
    int m = blockIdx.x;                   // 0..1983, m = t*64+b
    int t = m >> 6, b = m & 63;
    float* row = out + ((size_t)b * T_ + t + 1) * V_;
    int tid = threadIdx.x;
    float mx = -1e30f, sum = 0.f;
    for (int v4 = tid; v4 < V_ / 4; v4 += 256) {
        float4 x = ((const float4*)row)[v4];
        float m4 = fmaxf(fmaxf(x.x, x.y), fmaxf(x.z, x.w));
        if (m4 > mx) { sum *= __expf(mx - m4); mx = m4; }
        sum += __expf(x.x - mx) + __expf(x.y - mx) + __expf(x.z - mx) + __expf(x.w - mx);
    }
    rmx[tid] = mx; rsum[tid] = sum;
    __syncthreads();
    for (int s = 128; s > 0; s >>= 1) {
        if (tid < s) {
            float ma = rmx[tid], mb = rmx[tid + s];
            float sa = rsum[tid], sb = rsum[tid + s];
            float mm = fmaxf(ma, mb);
            rmx[tid] = mm;
            rsum[tid] = sa * __expf(ma - mm) + sb * __expf(mb - mm);
        }
        __syncthreads();
    }
    float lse = rmx[0] + logf(rsum[0]);
    for (int v4 = tid; v4 < V_ / 4; v4 += 256) {
        float4 x = ((const float4*)row)[v4];
        x.x -= lse; x.y -= lse; x.z -= lse; x.w -= lse;
        ((float4*)row)[v4] = x;
    }
}

extern "C" void kernel_launch(void* const* d_in, const int* in_sizes, int n_in,
                              void* d_out, int out_size, void* d_ws, size_t ws_size,
                              hipStream_t stream) {
    const float* X      = (const float*)d_in[0];
    const float* emb    = (const float*)d_in[1];
    const float* fc1_w  = (const float*)d_in[2];
    const float* fc1_b  = (const float*)d_in[3];
    const float* w_ih   = (const float*)d_in[4];
    const float* w_hh   = (const float*)d_in[5];
    const float* b_ih   = (const float*)d_in[6];
    const float* b_hh   = (const float*)d_in[7];
    const float* fc2_w  = (const float*)d_in[8];
    const float* fc2_b  = (const float*)d_in[9];
    const int*   label  = (const int*)d_in[10];
    float* out = (float*)d_out;

    char* ws = (char*)d_ws;
    float*          Xp     = (float*)(ws);                        // 65,536
    float*          gconst = (float*)(ws + 65536);                // 262,144
    unsigned short* gfullT = (unsigned short*)(ws + 327680);      // 31*1024*64*2 = 4,063,232
    unsigned short* hbuf0  = (unsigned short*)(ws + 4390912);     // 32,768
    unsigned short* hbuf1  = (unsigned short*)(ws + 4423680);     // 32,768
    __hip_bfloat16* Hs     = (__hip_bfloat16*)(ws + 4456448);     // 2048*256*2 = 1,048,576
    __hip_bfloat16* fc2bf  = (__hip_bfloat16*)(ws + 5505024);     // 10112*256*2 = 5,177,344
    unsigned int*   bar    = (unsigned int*)(ws + 10682368);      // 128
    // total = 10,682,496 bytes (< proven 14.68 MB budget)

    k_prep  <<<NPAD, 256, 0, stream>>>(fc2_w, fc2bf, Hs, hbuf0, bar);
    k_onehot<<<(B_ * V_ + 255) / 256, 256, 0, stream>>>(out);
    k_xp    <<<B_, 256, 0, stream>>>(X, fc1_w, fc1_b, Xp);
    k_gconst<<<B_, 256, 0, stream>>>(Xp, w_ih, b_ih, b_hh, gconst);
    k_ge    <<<dim3(4, 8, S_), 256, 0, stream>>>(emb, label, w_ih, gconst, gfullT);
    k_lstm  <<<LBLK, 256, 0, stream>>>(gfullT, w_hh, hbuf0, hbuf1, Hs, bar);
    k_gemm  <<<dim3(NPAD / 128, MPAD / 128), 256, 0, stream>>>((const unsigned short*)Hs,
                                                              (const unsigned short*)fc2bf, fc2_b, out);
    k_lsm   <<<S_ * B_, 256, 0, stream>>>(out);
}